// Round 3
// baseline (3917.146 us; speedup 1.0000x reference)
//
#include <hip/hip_runtime.h>
#include <math.h>

#define TT 50
#define BB 256
#define HH 256
#define MSZ 256
#define MDM 64
#define NRD 4
#define NCL 5
#define GAMMA_ 0.95f
#define EPS_ 1e-8f

__device__ __forceinline__ float sigf(float x){ return 1.f/(1.f + expf(-x)); }

// Monotone-counter grid barrier. Requires all 256 blocks co-resident
// (91KB LDS -> exactly 1 block/CU on 256 CUs; __launch_bounds__(256,1)).
__device__ __forceinline__ void gbar(unsigned* cnt, unsigned target){
  __syncthreads();
  if (threadIdx.x == 0){
    __threadfence();                     // release: publish our stores device-wide
    __hip_atomic_fetch_add(cnt, 1u, __ATOMIC_RELAXED, __HIP_MEMORY_SCOPE_AGENT);
    while (__hip_atomic_load(cnt, __ATOMIC_RELAXED, __HIP_MEMORY_SCOPE_AGENT) < target)
      __builtin_amdgcn_s_sleep(2);
    __threadfence();                     // acquire: invalidate before reading others' data
  }
  __syncthreads();
}

// ---------------- K_init: zero the barrier counter ----------------
__global__ void k_init(unsigned* bar){
  if (threadIdx.x == 0 && blockIdx.x == 0) *bar = 0u;
}

// ---------------- K1: X_proj = x_seq @ W_ih[:405] + b_lstm  (rows m = t*256+b) ----------------
__global__ __launch_bounds__(256) void k_xproj(
  const float* __restrict__ X, const int* __restrict__ tgt,
  const float* __restrict__ Wih, const float* __restrict__ bl,
  float* __restrict__ Xp)
{
  __shared__ float As[16*68];
  __shared__ float Bs[16*64];
  const int tid = threadIdx.x;
  const int m0 = blockIdx.x*64, j0 = blockIdx.y*64;
  const int tx = tid & 15, ty = tid >> 4;
  const int arow = tid >> 2, aseg = tid & 3;
  const int ma = m0 + arow;
  const float* Arow = X + ((ma & 255)*TT + (ma >> 8))*400;
  const int bkr = tid >> 4, bjs = tid & 15;
  float acc[4][4] = {};
  for (int k0 = 0; k0 < 400; k0 += 16) {
    float4 av = *(const float4*)(Arow + k0 + aseg*4);
    float4 bv = *(const float4*)(Wih + (k0 + bkr)*1024 + j0 + bjs*4);
    __syncthreads();
    As[(aseg*4+0)*68 + arow] = av.x;
    As[(aseg*4+1)*68 + arow] = av.y;
    As[(aseg*4+2)*68 + arow] = av.z;
    As[(aseg*4+3)*68 + arow] = av.w;
    *(float4*)&Bs[bkr*64 + bjs*4] = bv;
    __syncthreads();
#pragma unroll
    for (int kk = 0; kk < 16; ++kk) {
      float4 a4 = *(const float4*)&As[kk*68 + ty*4];
      float4 b4 = *(const float4*)&Bs[kk*64 + tx*4];
      acc[0][0] = fmaf(a4.x,b4.x,acc[0][0]); acc[0][1] = fmaf(a4.x,b4.y,acc[0][1]);
      acc[0][2] = fmaf(a4.x,b4.z,acc[0][2]); acc[0][3] = fmaf(a4.x,b4.w,acc[0][3]);
      acc[1][0] = fmaf(a4.y,b4.x,acc[1][0]); acc[1][1] = fmaf(a4.y,b4.y,acc[1][1]);
      acc[1][2] = fmaf(a4.y,b4.z,acc[1][2]); acc[1][3] = fmaf(a4.y,b4.w,acc[1][3]);
      acc[2][0] = fmaf(a4.z,b4.x,acc[2][0]); acc[2][1] = fmaf(a4.z,b4.y,acc[2][1]);
      acc[2][2] = fmaf(a4.z,b4.z,acc[2][2]); acc[2][3] = fmaf(a4.z,b4.w,acc[2][3]);
      acc[3][0] = fmaf(a4.w,b4.x,acc[3][0]); acc[3][1] = fmaf(a4.w,b4.y,acc[3][1]);
      acc[3][2] = fmaf(a4.w,b4.z,acc[3][2]); acc[3][3] = fmaf(a4.w,b4.w,acc[3][3]);
    }
  }
#pragma unroll
  for (int i = 0; i < 4; ++i){
    int m = m0 + ty*4 + i;
    int t = m >> 8, b = m & 255;
    const float* offrow = (t > 0) ? (Wih + (400 + tgt[b*TT + t - 1])*1024) : nullptr;
    int cj = j0 + tx*4;
    float4 r4;
    r4.x = acc[i][0] + bl[cj+0] + (offrow ? offrow[cj+0] : 0.f);
    r4.y = acc[i][1] + bl[cj+1] + (offrow ? offrow[cj+1] : 0.f);
    r4.z = acc[i][2] + bl[cj+2] + (offrow ? offrow[cj+2] : 0.f);
    r4.w = acc[i][3] + bl[cj+3] + (offrow ? offrow[cj+3] : 0.f);
    *(float4*)&Xp[m*1024 + cj] = r4;
  }
}

// ---------------- K2: persistent fused recurrent kernel ----------------
__global__ __launch_bounds__(256, 1) void k_persist(
  const float* __restrict__ Xp, const float* __restrict__ Wih,
  const float* __restrict__ Whh, const float* __restrict__ Wkp,
  const float* __restrict__ bkp, float* __restrict__ rh,
  float* __restrict__ gp, float* __restrict__ outs, unsigned* bar)
{
  extern __shared__ float sm[];
  float* Ms   = sm;            // 256*65 = 16640
  float* wrL  = sm + 16640;    // 1024
  float* wwL  = wrL + 1024;    // 1024
  float* simL = wwL + 1024;    // 1024
  float* wuL  = simL + 1024;   // 256
  float* kL   = wuL + 256;     // 256
  float* hL   = kL + 256;      // 256
  float* cL   = hL + 256;      // 256
  float* As   = cL + 256;      // 16*68 = 1088
  float* Bs   = As + 1088;     // 16*64 = 1024   -> total 22848 floats = 91392 B
  __shared__ unsigned long long redU[4];
  __shared__ int luS[4];
  __shared__ float alphaS[4];
  __shared__ float kinv[4];

  const int tid = threadIdx.x;
  const int b   = blockIdx.x;
  const int mt = blockIdx.x >> 6;
  const int jt = (blockIdx.x >> 2) & 15;
  const int p  = blockIdx.x & 3;
  const int m0 = mt*64, j0 = jt*64, kbase = p*128;
  const int tx = tid & 15, ty = tid >> 4;
  const int arow = tid >> 2, aseg = tid & 3;
  const int bkr = tid >> 4, bjs = tid & 15;

  // ---- init persistent per-batch state (ALL 256*64 elements of M!) ----
#pragma unroll
  for (int it = 0; it < 64; ++it){
    int i = it*256 + tid;                 // i in [0, 16384)
    Ms[(i >> 6)*65 + (i & 63)] = 1e-6f;   // row = i>>6 in [0,256)
  }
  *(float4*)&wrL[tid*4] = make_float4(1.f/256.f, 1.f/256.f, 1.f/256.f, 1.f/256.f);
  wuL[tid] = 1.f/256.f; cL[tid] = 0.f; hL[tid] = 0.f;
  rh[b*512 + tid] = 0.f;          // r0
  rh[b*512 + 256 + tid] = 0.f;    // h0

  unsigned ep = 256;
  gbar(bar, ep);

  for (int t = 0; t < TT; ++t){
    // ======== phase A: gates partial = rh-tile @ Wrec-tile (split-K p) ========
    {
      float acc[4][4] = {};
      for (int k0 = kbase; k0 < kbase + 128; k0 += 16){
        float4 av = *(const float4*)&rh[(m0 + arow)*512 + k0 + aseg*4];
        int kb = k0 + bkr;
        const float* bsrc = (kb < 256) ? (Wih + (405 + kb)*1024) : (Whh + (kb - 256)*1024);
        float4 bv = *(const float4*)(bsrc + j0 + bjs*4);
        __syncthreads();
        As[(aseg*4+0)*68 + arow] = av.x;
        As[(aseg*4+1)*68 + arow] = av.y;
        As[(aseg*4+2)*68 + arow] = av.z;
        As[(aseg*4+3)*68 + arow] = av.w;
        *(float4*)&Bs[bkr*64 + bjs*4] = bv;
        __syncthreads();
#pragma unroll
        for (int kk = 0; kk < 16; ++kk) {
          float4 a4 = *(const float4*)&As[kk*68 + ty*4];
          float4 b4 = *(const float4*)&Bs[kk*64 + tx*4];
          acc[0][0] = fmaf(a4.x,b4.x,acc[0][0]); acc[0][1] = fmaf(a4.x,b4.y,acc[0][1]);
          acc[0][2] = fmaf(a4.x,b4.z,acc[0][2]); acc[0][3] = fmaf(a4.x,b4.w,acc[0][3]);
          acc[1][0] = fmaf(a4.y,b4.x,acc[1][0]); acc[1][1] = fmaf(a4.y,b4.y,acc[1][1]);
          acc[1][2] = fmaf(a4.y,b4.z,acc[1][2]); acc[1][3] = fmaf(a4.y,b4.w,acc[1][3]);
          acc[2][0] = fmaf(a4.z,b4.x,acc[2][0]); acc[2][1] = fmaf(a4.z,b4.y,acc[2][1]);
          acc[2][2] = fmaf(a4.z,b4.z,acc[2][2]); acc[2][3] = fmaf(a4.z,b4.w,acc[2][3]);
          acc[3][0] = fmaf(a4.w,b4.x,acc[3][0]); acc[3][1] = fmaf(a4.w,b4.y,acc[3][1]);
          acc[3][2] = fmaf(a4.w,b4.z,acc[3][2]); acc[3][3] = fmaf(a4.w,b4.w,acc[3][3]);
        }
      }
      float* outp = gp + p*(BB*1024);
#pragma unroll
      for (int i = 0; i < 4; ++i){
        int bb = m0 + ty*4 + i;
        *(float4*)&outp[bb*1024 + j0 + tx*4] =
          make_float4(acc[i][0], acc[i][1], acc[i][2], acc[i][3]);
      }
    }
    ep += 256; gbar(bar, ep);

    // ======== phase B: LSTM pointwise + LRUA memory update for batch b ========
    {
      const float* xr = Xp + ((size_t)t*256 + b)*1024;
      const float* g0 = gp + b*1024;
      float g[4];
#pragma unroll
      for (int q = 0; q < 4; ++q){
        int col = q*256 + tid;
        g[q] = xr[col] + g0[col] + g0[262144 + col] + g0[524288 + col] + g0[786432 + col];
      }
      float cn = sigf(g[1])*cL[tid] + sigf(g[0])*tanhf(g[2]);
      float hn = sigf(g[3])*tanhf(cn);
      cL[tid] = cn; hL[tid] = hn;
      outs[((size_t)b*TT + t)*512 + tid] = hn;
      rh[b*512 + 256 + tid] = hn;
    }
    __syncthreads();
    // key projection p = h @ W_kp + b_kp
    for (int j = tid; j < 260; j += 256){
      float acc2 = bkp[j];
      for (int k = 0; k < 256; ++k) acc2 = fmaf(hL[k], Wkp[k*260 + j], acc2);
      if (j < 256) kL[j] = tanhf(acc2);
      else alphaS[j-256] = sigf(acc2);
    }
    __syncthreads();
    if (tid < 4){
      float s = 0.f;
      for (int d = 0; d < 64; ++d){ float v = kL[tid*64+d]; s = fmaf(v,v,s); }
      kinv[tid] = 1.f/(sqrtf(s) + EPS_);
    }
    // top-4 argmin of w_u, ties -> lowest index
    unsigned long long mykey =
        (((unsigned long long)__float_as_uint(wuL[tid])) << 32) | (unsigned)tid;
    for (int round = 0; round < 4; ++round){
      __syncthreads();
      unsigned long long key = mykey;
      for (int rr = 0; rr < round; ++rr) if (luS[rr] == tid) key = ~0ull;
      for (int o = 32; o; o >>= 1){
        unsigned long long other = __shfl_xor(key, o, 64);
        if (other < key) key = other;
      }
      if ((tid & 63) == 0) redU[tid >> 6] = key;
      __syncthreads();
      if (tid == 0){
        unsigned long long k0 = redU[0];
        if (redU[1] < k0) k0 = redU[1];
        if (redU[2] < k0) k0 = redU[2];
        if (redU[3] < k0) k0 = redU[3];
        luS[round] = (int)(unsigned)(k0 & 0xffffffffull);
      }
    }
    __syncthreads();
    // write weights
#pragma unroll
    for (int r = 0; r < 4; ++r){
      float a = alphaS[r];
      float w = a * wrL[r*256 + tid];
      if (tid == luS[r]) w += 1.f - a;
      wwL[r*256 + tid] = w;
    }
    __syncthreads();
    // erase lu[0] row, additive write, row norm + cosine sim (thread = slot)
    {
      const int n = tid;
      float w0 = wwL[n], w1 = wwL[256+n], w2 = wwL[512+n], w3 = wwL[768+n];
      const bool er = (n == luS[0]);
      float* row = Ms + n*65;
      float nsq = 0.f, s0 = 0.f, s1 = 0.f, s2 = 0.f, s3 = 0.f;
#pragma unroll
      for (int d = 0; d < 64; ++d){
        float m = er ? 0.f : row[d];
        m = fmaf(w0, kL[d],     m);
        m = fmaf(w1, kL[64+d],  m);
        m = fmaf(w2, kL[128+d], m);
        m = fmaf(w3, kL[192+d], m);
        row[d] = m;
        nsq = fmaf(m, m, nsq);
        s0 = fmaf(kL[d],     m, s0);
        s1 = fmaf(kL[64+d],  m, s1);
        s2 = fmaf(kL[128+d], m, s2);
        s3 = fmaf(kL[192+d], m, s3);
      }
      float minv = 1.f/(sqrtf(nsq) + EPS_);
      simL[n]     = s0 * kinv[0] * minv;
      simL[256+n] = s1 * kinv[1] * minv;
      simL[512+n] = s2 * kinv[2] * minv;
      simL[768+n] = s3 * kinv[3] * minv;
    }
    __syncthreads();
    // softmax over slots, one wave per read head
    {
      const int r = tid >> 6, l = tid & 63;
      float v0 = simL[r*256 + l],       v1 = simL[r*256 + 64 + l],
            v2 = simL[r*256 + 128 + l], v3 = simL[r*256 + 192 + l];
      float mx = fmaxf(fmaxf(v0,v1), fmaxf(v2,v3));
      for (int o = 32; o; o >>= 1) mx = fmaxf(mx, __shfl_xor(mx, o, 64));
      float e0 = expf(v0-mx), e1 = expf(v1-mx), e2 = expf(v2-mx), e3 = expf(v3-mx);
      float s = e0+e1+e2+e3;
      for (int o = 32; o; o >>= 1) s += __shfl_xor(s, o, 64);
      float inv = 1.f/s;
      wrL[r*256 + l] = e0*inv; wrL[r*256 + 64 + l] = e1*inv;
      wrL[r*256 + 128 + l] = e2*inv; wrL[r*256 + 192 + l] = e3*inv;
    }
    __syncthreads();
    // reads = w_r @ M ; usage update
    {
      const int r = tid >> 6, d = tid & 63;
      float acc3 = 0.f;
      for (int n = 0; n < 256; ++n) acc3 = fmaf(wrL[r*256+n], Ms[n*65+d], acc3);
      outs[((size_t)b*TT + t)*512 + 256 + tid] = acc3;
      rh[b*512 + tid] = acc3;
    }
    {
      float wu = GAMMA_*wuL[tid]
        + wrL[tid] + wrL[256+tid] + wrL[512+tid] + wrL[768+tid]
        + wwL[tid] + wwL[256+tid] + wwL[512+tid] + wwL[768+tid];
      wuL[tid] = wu;
    }
    ep += 256; gbar(bar, ep);
  }
}

// ---------------- K4: logits + softmax (one wave per (b,t) row) ----------------
__global__ __launch_bounds__(256) void k_out(
  const float* __restrict__ outs, const float* __restrict__ Wout,
  const float* __restrict__ bout, float* __restrict__ out)
{
  const int m = blockIdx.x*4 + (threadIdx.x >> 6);
  const int l = threadIdx.x & 63;
  const float* row = outs + m*512;
  float a0=0,a1=0,a2=0,a3=0,a4=0;
#pragma unroll
  for (int q = 0; q < 8; ++q){
    int e = q*64 + l;
    float v = row[e];
    const float* w = Wout + e*5;
    a0 = fmaf(v,w[0],a0); a1 = fmaf(v,w[1],a1); a2 = fmaf(v,w[2],a2);
    a3 = fmaf(v,w[3],a3); a4 = fmaf(v,w[4],a4);
  }
  for (int o = 32; o; o >>= 1){
    a0 += __shfl_xor(a0,o,64); a1 += __shfl_xor(a1,o,64); a2 += __shfl_xor(a2,o,64);
    a3 += __shfl_xor(a3,o,64); a4 += __shfl_xor(a4,o,64);
  }
  if (l == 0){
    float l0=a0+bout[0], l1=a1+bout[1], l2=a2+bout[2], l3=a3+bout[3], l4=a4+bout[4];
    float mx = fmaxf(fmaxf(fmaxf(l0,l1),fmaxf(l2,l3)),l4);
    float e0=expf(l0-mx),e1=expf(l1-mx),e2=expf(l2-mx),e3=expf(l3-mx),e4=expf(l4-mx);
    float inv = 1.f/(e0+e1+e2+e3+e4);
    float* o5 = out + m*5;
    o5[0]=e0*inv; o5[1]=e1*inv; o5[2]=e2*inv; o5[3]=e3*inv; o5[4]=e4*inv;
  }
}

extern "C" void kernel_launch(void* const* d_in, const int* in_sizes, int n_in,
                              void* d_out, int out_size, void* d_ws, size_t ws_size,
                              hipStream_t stream)
{
  (void)in_sizes; (void)n_in; (void)out_size; (void)ws_size;
  const float* X    = (const float*)d_in[0];
  const int*   tgt  = (const int*)d_in[1];
  const float* Wih  = (const float*)d_in[2];
  const float* Whh  = (const float*)d_in[3];
  const float* bl   = (const float*)d_in[4];
  const float* Wkp  = (const float*)d_in[5];
  const float* bkp  = (const float*)d_in[6];
  const float* Wout = (const float*)d_in[7];
  const float* bout = (const float*)d_in[8];
  float* out = (float*)d_out;

  float* ws   = (float*)d_ws;
  float* Xp   = ws;                    // 13,107,200 floats  [T*B, 1024]
  float* outs = Xp + 13107200;         //  6,553,600         [B*T, 512]
  float* gp   = outs + 6553600;        //  1,048,576         [4][B,1024] split-K partials
  float* rh   = gp + 1048576;          //    131,072         [B, 512] = [r | h]
  unsigned* bar = (unsigned*)(rh + 131072);

  hipFuncSetAttribute(reinterpret_cast<const void*>(k_persist),
                      hipFuncAttributeMaxDynamicSharedMemorySize, 91392);

  k_init<<<1, 64, 0, stream>>>(bar);
  k_xproj<<<dim3(200,16), 256, 0, stream>>>(X, tgt, Wih, bl, Xp);
  k_persist<<<256, 256, 91392, stream>>>(Xp, Wih, Whh, Wkp, bkp, rh, gp, outs, bar);
  k_out<<<3200, 256, 0, stream>>>(outs, Wout, bout, out);
}

// Round 4
// 1929.922 us; speedup vs baseline: 2.0297x; 2.0297x over previous
//
#include <hip/hip_runtime.h>
#include <math.h>

#define TT 50
#define BB 256
#define HH 256
#define MSZ 256
#define MDM 64
#define NRD 4
#define NCL 5
#define GAMMA_ 0.95f
#define EPS_ 1e-8f

__device__ __forceinline__ float sigf(float x){ return 1.f/(1.f + expf(-x)); }

// ---------------- K1: X_proj = x_seq @ W_ih[:405] + b_lstm  (rows m = t*256+b) ----------------
__global__ __launch_bounds__(256) void k_xproj(
  const float* __restrict__ X, const int* __restrict__ tgt,
  const float* __restrict__ Wih, const float* __restrict__ bl,
  float* __restrict__ Xp)
{
  __shared__ float As[16*68];
  __shared__ float Bs[16*64];
  const int tid = threadIdx.x;
  const int m0 = blockIdx.x*64, j0 = blockIdx.y*64;
  const int tx = tid & 15, ty = tid >> 4;
  const int arow = tid >> 2, aseg = tid & 3;
  const int ma = m0 + arow;
  const float* Arow = X + ((ma & 255)*TT + (ma >> 8))*400;
  const int bkr = tid >> 4, bjs = tid & 15;
  float acc[4][4] = {};
  for (int k0 = 0; k0 < 400; k0 += 16) {
    float4 av = *(const float4*)(Arow + k0 + aseg*4);
    float4 bv = *(const float4*)(Wih + (k0 + bkr)*1024 + j0 + bjs*4);
    __syncthreads();
    As[(aseg*4+0)*68 + arow] = av.x;
    As[(aseg*4+1)*68 + arow] = av.y;
    As[(aseg*4+2)*68 + arow] = av.z;
    As[(aseg*4+3)*68 + arow] = av.w;
    *(float4*)&Bs[bkr*64 + bjs*4] = bv;
    __syncthreads();
#pragma unroll
    for (int kk = 0; kk < 16; ++kk) {
      float4 a4 = *(const float4*)&As[kk*68 + ty*4];
      float4 b4 = *(const float4*)&Bs[kk*64 + tx*4];
      acc[0][0] = fmaf(a4.x,b4.x,acc[0][0]); acc[0][1] = fmaf(a4.x,b4.y,acc[0][1]);
      acc[0][2] = fmaf(a4.x,b4.z,acc[0][2]); acc[0][3] = fmaf(a4.x,b4.w,acc[0][3]);
      acc[1][0] = fmaf(a4.y,b4.x,acc[1][0]); acc[1][1] = fmaf(a4.y,b4.y,acc[1][1]);
      acc[1][2] = fmaf(a4.y,b4.z,acc[1][2]); acc[1][3] = fmaf(a4.y,b4.w,acc[1][3]);
      acc[2][0] = fmaf(a4.z,b4.x,acc[2][0]); acc[2][1] = fmaf(a4.z,b4.y,acc[2][1]);
      acc[2][2] = fmaf(a4.z,b4.z,acc[2][2]); acc[2][3] = fmaf(a4.z,b4.w,acc[2][3]);
      acc[3][0] = fmaf(a4.w,b4.x,acc[3][0]); acc[3][1] = fmaf(a4.w,b4.y,acc[3][1]);
      acc[3][2] = fmaf(a4.w,b4.z,acc[3][2]); acc[3][3] = fmaf(a4.w,b4.w,acc[3][3]);
    }
  }
#pragma unroll
  for (int i = 0; i < 4; ++i){
    int m = m0 + ty*4 + i;
    int t = m >> 8, b = m & 255;
    const float* offrow = (t > 0) ? (Wih + (400 + tgt[b*TT + t - 1])*1024) : nullptr;
    int cj = j0 + tx*4;
    float4 r4;
    r4.x = acc[i][0] + bl[cj+0] + (offrow ? offrow[cj+0] : 0.f);
    r4.y = acc[i][1] + bl[cj+1] + (offrow ? offrow[cj+1] : 0.f);
    r4.z = acc[i][2] + bl[cj+2] + (offrow ? offrow[cj+2] : 0.f);
    r4.w = acc[i][3] + bl[cj+3] + (offrow ? offrow[cj+3] : 0.f);
    *(float4*)&Xp[m*1024 + cj] = r4;
  }
}

#define FMA4(vv, ww) { acc4.x = fmaf(vv, ww.x, acc4.x); acc4.y = fmaf(vv, ww.y, acc4.y); \
                       acc4.z = fmaf(vv, ww.z, acc4.z); acc4.w = fmaf(vv, ww.w, acc4.w); }

// ---------------- K2: per-batch fully-independent recurrent kernel ----------------
// One block per batch element. M/wr/wu/c/h/reads live in LDS for all 50 steps.
// No grid sync, no fences: batches are independent. Weights stream from XCD L2
// (W_rec 2.1MB + Wkp 0.27MB + Wout 10KB < 4MiB per-XCD L2, cached across steps).
__global__ __launch_bounds__(256) void k_batch(
  const float* __restrict__ Xp, const float* __restrict__ Wih,
  const float* __restrict__ Whh, const float* __restrict__ Wkp,
  const float* __restrict__ bkp, const float* __restrict__ Wout,
  const float* __restrict__ bout, float* __restrict__ out)
{
  extern __shared__ float sm[];
  float* Ms    = sm;             // 256*65 = 16640 (padded rows)
  float* gL    = sm + 16640;     // 1024 gates
  float* wrL   = gL + 1024;      // 1024
  float* wwL   = wrL + 1024;     // 1024
  float* simL  = wwL + 1024;     // 1024 (also alpha-partial scratch)
  float* pL    = simL + 1024;    // 1280 logit partials
  float* wuL   = pL + 1280;      // 256
  float* vL    = wuL + 256;      // 512 = [reads(256) | h(256)]  (GEMV input vector)
  float* cL    = vL + 512;       // 256
  float* kL    = cL + 256;       // 256
  float* WoutL = kL + 256;       // 2560   -> total 25856 floats = 103424 B
  __shared__ unsigned long long redU[4];
  __shared__ int luS[4];
  __shared__ float alphaS[4];
  __shared__ float kinv[4];
  __shared__ float logitS[8];
  __shared__ float boutS[8];

  const int tid = threadIdx.x;
  const int b   = blockIdx.x;

  // ---- init persistent per-batch state ----
#pragma unroll
  for (int it = 0; it < 64; ++it){
    int i = it*256 + tid;
    Ms[(i >> 6)*65 + (i & 63)] = 1e-6f;
  }
  *(float4*)&wrL[tid*4] = make_float4(1.f/256.f, 1.f/256.f, 1.f/256.f, 1.f/256.f);
  wuL[tid] = 1.f/256.f; cL[tid] = 0.f; vL[tid] = 0.f; vL[256+tid] = 0.f;
  for (int i = tid; i < 2560; i += 256) WoutL[i] = Wout[i];
  if (tid < 5) boutS[tid] = bout[tid];
  __syncthreads();

  for (int t = 0; t < TT; ++t){
    // ---- GEMV: gates = Xp_row + [r|h] @ [Wih[405:]; Whh]  (thread owns cols tid*4..+3) ----
    {
      const float* xr = Xp + ((size_t)t*256 + b)*1024;
      float4 acc4 = *(const float4*)(xr + tid*4);
      const float* Wr = Wih + (size_t)405*1024 + tid*4;
      for (int k = 0; k < 256; k += 8){
        float4 va = *(const float4*)&vL[k];
        float4 vb = *(const float4*)&vL[k+4];
        float4 w0 = *(const float4*)(Wr + (size_t)(k+0)*1024);
        float4 w1 = *(const float4*)(Wr + (size_t)(k+1)*1024);
        float4 w2 = *(const float4*)(Wr + (size_t)(k+2)*1024);
        float4 w3 = *(const float4*)(Wr + (size_t)(k+3)*1024);
        float4 w4 = *(const float4*)(Wr + (size_t)(k+4)*1024);
        float4 w5 = *(const float4*)(Wr + (size_t)(k+5)*1024);
        float4 w6 = *(const float4*)(Wr + (size_t)(k+6)*1024);
        float4 w7 = *(const float4*)(Wr + (size_t)(k+7)*1024);
        FMA4(va.x, w0) FMA4(va.y, w1) FMA4(va.z, w2) FMA4(va.w, w3)
        FMA4(vb.x, w4) FMA4(vb.y, w5) FMA4(vb.z, w6) FMA4(vb.w, w7)
      }
      const float* Wh = Whh + tid*4;
      for (int k = 0; k < 256; k += 8){
        float4 va = *(const float4*)&vL[256+k];
        float4 vb = *(const float4*)&vL[256+k+4];
        float4 w0 = *(const float4*)(Wh + (size_t)(k+0)*1024);
        float4 w1 = *(const float4*)(Wh + (size_t)(k+1)*1024);
        float4 w2 = *(const float4*)(Wh + (size_t)(k+2)*1024);
        float4 w3 = *(const float4*)(Wh + (size_t)(k+3)*1024);
        float4 w4 = *(const float4*)(Wh + (size_t)(k+4)*1024);
        float4 w5 = *(const float4*)(Wh + (size_t)(k+5)*1024);
        float4 w6 = *(const float4*)(Wh + (size_t)(k+6)*1024);
        float4 w7 = *(const float4*)(Wh + (size_t)(k+7)*1024);
        FMA4(va.x, w0) FMA4(va.y, w1) FMA4(va.z, w2) FMA4(va.w, w3)
        FMA4(vb.x, w4) FMA4(vb.y, w5) FMA4(vb.z, w6) FMA4(vb.w, w7)
      }
      *(float4*)&gL[tid*4] = acc4;
    }
    __syncthreads();

    // ---- LSTM pointwise (thread = hidden unit) ----
    {
      float gi = gL[tid], gf = gL[256+tid], gg = gL[512+tid], go = gL[768+tid];
      float cn = sigf(gf)*cL[tid] + sigf(gi)*tanhf(gg);
      float hn = sigf(go)*tanhf(cn);
      cL[tid] = cn; vL[256+tid] = hn;
    }
    __syncthreads();

    // ---- key projection: kL[j] = tanh(h @ Wkp[:,j] + bkp[j]); alpha partials -> simL ----
    {
      float acc = bkp[tid];
      const float* Wc = Wkp + tid;
      for (int k = 0; k < 256; k += 4){
        float4 vv = *(const float4*)&vL[256+k];
        acc = fmaf(vv.x, Wc[(size_t)(k+0)*260], acc);
        acc = fmaf(vv.y, Wc[(size_t)(k+1)*260], acc);
        acc = fmaf(vv.z, Wc[(size_t)(k+2)*260], acc);
        acc = fmaf(vv.w, Wc[(size_t)(k+3)*260], acc);
      }
      kL[tid] = tanhf(acc);
      float hv = vL[256+tid];
      const float* Wa = Wkp + tid*260 + 256;
      simL[tid]     = hv*Wa[0];
      simL[256+tid] = hv*Wa[1];
      simL[512+tid] = hv*Wa[2];
      simL[768+tid] = hv*Wa[3];
    }
    __syncthreads();

    // ---- alpha (4 wave reductions) + key inverse norms ----
    {
      const int w = tid >> 6, l = tid & 63;
      float s = simL[w*256+l] + simL[w*256+64+l] + simL[w*256+128+l] + simL[w*256+192+l];
      for (int o = 32; o; o >>= 1) s += __shfl_xor(s, o, 64);
      float kv = kL[w*64 + l];
      float sq = kv*kv;
      for (int o = 32; o; o >>= 1) sq += __shfl_xor(sq, o, 64);
      if (l == 0){
        alphaS[w] = sigf(s + bkp[256 + w]);
        kinv[w]   = 1.f/(sqrtf(sq) + EPS_);
      }
    }

    // ---- top-4 argmin of w_u (ties -> lowest index) ----
    {
      unsigned long long mykey =
          (((unsigned long long)__float_as_uint(wuL[tid])) << 32) | (unsigned)tid;
      for (int round = 0; round < 4; ++round){
        __syncthreads();
        unsigned long long key = mykey;
        for (int rr = 0; rr < round; ++rr) if (luS[rr] == tid) key = ~0ull;
        for (int o = 32; o; o >>= 1){
          unsigned long long other = __shfl_xor(key, o, 64);
          if (other < key) key = other;
        }
        if ((tid & 63) == 0) redU[tid >> 6] = key;
        __syncthreads();
        if (tid == 0){
          unsigned long long k0 = redU[0];
          if (redU[1] < k0) k0 = redU[1];
          if (redU[2] < k0) k0 = redU[2];
          if (redU[3] < k0) k0 = redU[3];
          luS[round] = (int)(unsigned)(k0 & 0xffffffffull);
        }
      }
    }
    __syncthreads();

    // ---- write weights ----
#pragma unroll
    for (int r = 0; r < 4; ++r){
      float a = alphaS[r];
      float w = a * wrL[r*256 + tid];
      if (tid == luS[r]) w += 1.f - a;
      wwL[r*256 + tid] = w;
    }
    __syncthreads();

    // ---- erase lu[0], additive write, row norm + cosine sim (thread = slot) ----
    {
      const int n = tid;
      float w0 = wwL[n], w1 = wwL[256+n], w2 = wwL[512+n], w3 = wwL[768+n];
      const bool er = (n == luS[0]);
      float* row = Ms + n*65;
      float nsq = 0.f, s0 = 0.f, s1 = 0.f, s2 = 0.f, s3 = 0.f;
#pragma unroll
      for (int d = 0; d < 64; ++d){
        float m = er ? 0.f : row[d];
        m = fmaf(w0, kL[d],     m);
        m = fmaf(w1, kL[64+d],  m);
        m = fmaf(w2, kL[128+d], m);
        m = fmaf(w3, kL[192+d], m);
        row[d] = m;
        nsq = fmaf(m, m, nsq);
        s0 = fmaf(kL[d],     m, s0);
        s1 = fmaf(kL[64+d],  m, s1);
        s2 = fmaf(kL[128+d], m, s2);
        s3 = fmaf(kL[192+d], m, s3);
      }
      float minv = 1.f/(sqrtf(nsq) + EPS_);
      simL[n]     = s0 * kinv[0] * minv;
      simL[256+n] = s1 * kinv[1] * minv;
      simL[512+n] = s2 * kinv[2] * minv;
      simL[768+n] = s3 * kinv[3] * minv;
    }
    __syncthreads();

    // ---- softmax over slots (one wave per read head) ----
    {
      const int r = tid >> 6, l = tid & 63;
      float v0 = simL[r*256 + l],       v1 = simL[r*256 + 64 + l],
            v2 = simL[r*256 + 128 + l], v3 = simL[r*256 + 192 + l];
      float mx = fmaxf(fmaxf(v0,v1), fmaxf(v2,v3));
      for (int o = 32; o; o >>= 1) mx = fmaxf(mx, __shfl_xor(mx, o, 64));
      float e0 = expf(v0-mx), e1 = expf(v1-mx), e2 = expf(v2-mx), e3 = expf(v3-mx);
      float s = e0+e1+e2+e3;
      for (int o = 32; o; o >>= 1) s += __shfl_xor(s, o, 64);
      float inv = 1.f/s;
      wrL[r*256 + l] = e0*inv; wrL[r*256 + 64 + l] = e1*inv;
      wrL[r*256 + 128 + l] = e2*inv; wrL[r*256 + 192 + l] = e3*inv;
    }
    __syncthreads();

    // ---- reads = w_r @ M  (thread = (r,d), result lands at vL[tid]) ; usage ----
    {
      const int r = tid >> 6, d = tid & 63;
      float acc3 = 0.f;
      for (int n = 0; n < 256; ++n) acc3 = fmaf(wrL[r*256+n], Ms[n*65+d], acc3);
      vL[tid] = acc3;                       // reads vector (next step's r; epilogue input)
    }
    {
      float wu = GAMMA_*wuL[tid]
        + wrL[tid] + wrL[256+tid] + wrL[512+tid] + wrL[768+tid]
        + wwL[tid] + wwL[256+tid] + wwL[512+tid] + wwL[768+tid];
      wuL[tid] = wu;
    }

    // ---- fused output head: logits = [h|reads] @ Wout + bout, softmax over 5 ----
    {
      float hv = vL[256+tid];               // own-thread values: no sync needed yet
      float rv = vL[tid];
      const float* W1 = WoutL + tid*5;          // row e = tid      (h part)
      const float* W2 = WoutL + (256+tid)*5;    // row e = 256+tid  (reads part)
      pL[0*256+tid] = hv*W1[0] + rv*W2[0];
      pL[1*256+tid] = hv*W1[1] + rv*W2[1];
      pL[2*256+tid] = hv*W1[2] + rv*W2[2];
      pL[3*256+tid] = hv*W1[3] + rv*W2[3];
      pL[4*256+tid] = hv*W1[4] + rv*W2[4];
    }
    __syncthreads();
    {
      const int w = tid >> 6, l = tid & 63;
      float s = pL[w*256+l] + pL[w*256+64+l] + pL[w*256+128+l] + pL[w*256+192+l];
      for (int o = 32; o; o >>= 1) s += __shfl_xor(s, o, 64);
      if (l == 0) logitS[w] = s + boutS[w];
      if (w == 0){
        float s4 = pL[1024+l] + pL[1024+64+l] + pL[1024+128+l] + pL[1024+192+l];
        for (int o = 32; o; o >>= 1) s4 += __shfl_xor(s4, o, 64);
        if (l == 0) logitS[4] = s4 + boutS[4];
      }
    }
    __syncthreads();
    if (tid == 0){
      float l0 = logitS[0], l1 = logitS[1], l2 = logitS[2], l3 = logitS[3], l4 = logitS[4];
      float mx = fmaxf(fmaxf(fmaxf(l0,l1), fmaxf(l2,l3)), l4);
      float e0 = expf(l0-mx), e1 = expf(l1-mx), e2 = expf(l2-mx), e3 = expf(l3-mx), e4 = expf(l4-mx);
      float inv = 1.f/(e0+e1+e2+e3+e4);
      float* o5 = out + ((size_t)b*TT + t)*NCL;
      o5[0] = e0*inv; o5[1] = e1*inv; o5[2] = e2*inv; o5[3] = e3*inv; o5[4] = e4*inv;
    }
    __syncthreads();
  }
}

extern "C" void kernel_launch(void* const* d_in, const int* in_sizes, int n_in,
                              void* d_out, int out_size, void* d_ws, size_t ws_size,
                              hipStream_t stream)
{
  (void)in_sizes; (void)n_in; (void)out_size; (void)ws_size;
  const float* X    = (const float*)d_in[0];
  const int*   tgt  = (const int*)d_in[1];
  const float* Wih  = (const float*)d_in[2];
  const float* Whh  = (const float*)d_in[3];
  const float* bl   = (const float*)d_in[4];
  const float* Wkp  = (const float*)d_in[5];
  const float* bkp  = (const float*)d_in[6];
  const float* Wout = (const float*)d_in[7];
  const float* bout = (const float*)d_in[8];
  float* out = (float*)d_out;

  float* Xp = (float*)d_ws;   // 13,107,200 floats  [T*B, 1024]

  hipFuncSetAttribute(reinterpret_cast<const void*>(k_batch),
                      hipFuncAttributeMaxDynamicSharedMemorySize, 103424);

  k_xproj<<<dim3(200,16), 256, 0, stream>>>(X, tgt, Wih, bl, Xp);
  k_batch<<<256, 256, 103424, stream>>>(Xp, Wih, Whh, Wkp, bkp, Wout, bout, out);
}

// Round 5
// 1188.760 us; speedup vs baseline: 3.2952x; 1.6235x over previous
//
#include <hip/hip_runtime.h>
#include <math.h>

#define TT 50
#define BB 256
#define HH 256
#define MSZ 256
#define MDM 64
#define NRD 4
#define NCL 5
#define GAMMA_ 0.95f
#define EPS_ 1e-8f

typedef unsigned int uint;

__device__ __forceinline__ float sigf(float x){ return 1.f/(1.f + expf(-x)); }
__device__ __forceinline__ uint f2bf(float f){          // RNE float->bf16 (low 16 bits)
  uint u = __float_as_uint(f);
  return (u + 0x7fffu + ((u >> 16) & 1u)) >> 16;
}
__device__ __forceinline__ float blo(uint u){ return __uint_as_float(u << 16); }
__device__ __forceinline__ float bhi(uint u){ return __uint_as_float(u & 0xffff0000u); }

// ---------------- K0: pack recurrent weights to bf16 (k-pair interleaved) ----------------
// Wpk[kp*1024 + c] = bf16(Wrec[2kp][c]) | bf16(Wrec[2kp+1][c])<<16,  Wrec = [Wih rows 405..660; Whh]
// Wkpu[ip*256 + j] = bf16(Wkp[2ip][j]) | bf16(Wkp[2ip+1][j])<<16     (key cols only, j<256)
// Wa4[j] = Wkp[j*260 + 256..259]  (alpha cols, fp32, repacked contiguous)
__global__ __launch_bounds__(256) void k_pack(
  const float* __restrict__ Wih, const float* __restrict__ Whh,
  const float* __restrict__ Wkp, uint* __restrict__ Wpk,
  uint* __restrict__ Wkpu, float4* __restrict__ Wa4)
{
  int i = blockIdx.x*256 + threadIdx.x;
  if (i < 262144){
    int kp = i >> 10, c = i & 1023;
    int k0 = 2*kp, k1 = k0 + 1;
    float v0 = (k0 < 256) ? Wih[(405+k0)*1024 + c] : Whh[(k0-256)*1024 + c];
    float v1 = (k1 < 256) ? Wih[(405+k1)*1024 + c] : Whh[(k1-256)*1024 + c];
    Wpk[kp*1024 + c] = f2bf(v0) | (f2bf(v1) << 16);
  } else if (i < 294912){
    int j = i - 262144; int ip = j >> 8, jj = j & 255;
    float v0 = Wkp[(2*ip)*260 + jj], v1 = Wkp[(2*ip+1)*260 + jj];
    Wkpu[ip*256 + jj] = f2bf(v0) | (f2bf(v1) << 16);
  } else if (i < 295168){
    int j = i - 294912;
    const float* Wa = Wkp + j*260 + 256;
    Wa4[j] = make_float4(Wa[0], Wa[1], Wa[2], Wa[3]);
  }
}

// ---------------- K1: X_proj = x_seq @ W_ih[:405] + b_lstm  (rows m = t*256+b) ----------------
__global__ __launch_bounds__(256) void k_xproj(
  const float* __restrict__ X, const int* __restrict__ tgt,
  const float* __restrict__ Wih, const float* __restrict__ bl,
  float* __restrict__ Xp)
{
  __shared__ float As[16*68];
  __shared__ float Bs[16*64];
  const int tid = threadIdx.x;
  const int m0 = blockIdx.x*64, j0 = blockIdx.y*64;
  const int tx = tid & 15, ty = tid >> 4;
  const int arow = tid >> 2, aseg = tid & 3;
  const int ma = m0 + arow;
  const float* Arow = X + ((ma & 255)*TT + (ma >> 8))*400;
  const int bkr = tid >> 4, bjs = tid & 15;
  float acc[4][4] = {};
  for (int k0 = 0; k0 < 400; k0 += 16) {
    float4 av = *(const float4*)(Arow + k0 + aseg*4);
    float4 bv = *(const float4*)(Wih + (k0 + bkr)*1024 + j0 + bjs*4);
    __syncthreads();
    As[(aseg*4+0)*68 + arow] = av.x;
    As[(aseg*4+1)*68 + arow] = av.y;
    As[(aseg*4+2)*68 + arow] = av.z;
    As[(aseg*4+3)*68 + arow] = av.w;
    *(float4*)&Bs[bkr*64 + bjs*4] = bv;
    __syncthreads();
#pragma unroll
    for (int kk = 0; kk < 16; ++kk) {
      float4 a4 = *(const float4*)&As[kk*68 + ty*4];
      float4 b4 = *(const float4*)&Bs[kk*64 + tx*4];
      acc[0][0] = fmaf(a4.x,b4.x,acc[0][0]); acc[0][1] = fmaf(a4.x,b4.y,acc[0][1]);
      acc[0][2] = fmaf(a4.x,b4.z,acc[0][2]); acc[0][3] = fmaf(a4.x,b4.w,acc[0][3]);
      acc[1][0] = fmaf(a4.y,b4.x,acc[1][0]); acc[1][1] = fmaf(a4.y,b4.y,acc[1][1]);
      acc[1][2] = fmaf(a4.y,b4.z,acc[1][2]); acc[1][3] = fmaf(a4.y,b4.w,acc[1][3]);
      acc[2][0] = fmaf(a4.z,b4.x,acc[2][0]); acc[2][1] = fmaf(a4.z,b4.y,acc[2][1]);
      acc[2][2] = fmaf(a4.z,b4.z,acc[2][2]); acc[2][3] = fmaf(a4.z,b4.w,acc[2][3]);
      acc[3][0] = fmaf(a4.w,b4.x,acc[3][0]); acc[3][1] = fmaf(a4.w,b4.y,acc[3][1]);
      acc[3][2] = fmaf(a4.w,b4.z,acc[3][2]); acc[3][3] = fmaf(a4.w,b4.w,acc[3][3]);
    }
  }
#pragma unroll
  for (int i = 0; i < 4; ++i){
    int m = m0 + ty*4 + i;
    int t = m >> 8, b = m & 255;
    const float* offrow = (t > 0) ? (Wih + (400 + tgt[b*TT + t - 1])*1024) : nullptr;
    int cj = j0 + tx*4;
    float4 r4;
    r4.x = acc[i][0] + bl[cj+0] + (offrow ? offrow[cj+0] : 0.f);
    r4.y = acc[i][1] + bl[cj+1] + (offrow ? offrow[cj+1] : 0.f);
    r4.z = acc[i][2] + bl[cj+2] + (offrow ? offrow[cj+2] : 0.f);
    r4.w = acc[i][3] + bl[cj+3] + (offrow ? offrow[cj+3] : 0.f);
    *(float4*)&Xp[m*1024 + cj] = r4;
  }
}

#define FMA4(vv, ww) { acc4.x = fmaf(vv, ww.x, acc4.x); acc4.y = fmaf(vv, ww.y, acc4.y); \
                       acc4.z = fmaf(vv, ww.z, acc4.z); acc4.w = fmaf(vv, ww.w, acc4.w); }

// ---------------- K2: per-batch recurrent kernel, 512 threads (8 waves/CU) ----------------
// One block per batch element; M/wr/wu/c/h in LDS for all 50 steps. GEMVs stream
// bf16-packed weights from XCD L2 (1.2 MB/CU/step), K-split across the 8 waves.
__global__ __launch_bounds__(512, 2) void k_batch(
  const float* __restrict__ Xp, const uint* __restrict__ Wpk,
  const uint* __restrict__ Wkpu, const float4* __restrict__ Wa4,
  const float* __restrict__ bkp, const float* __restrict__ Wout,
  const float* __restrict__ bout, float* __restrict__ out)
{
  extern __shared__ float sm[];
  float* Ms    = sm;             // 256*65 = 16640 (padded rows: bank = (n+d)%32)
  float* gL    = sm + 16640;     // 1024 gates
  float* wrL   = gL + 1024;      // 1024
  float* wwL   = wrL + 1024;     // 1024
  float* simL  = wwL + 1024;     // 1024
  float* scr   = simL + 1024;    // 2560 scratch: GEMV/keyproj/cosine/reads partials + logit pL
  float* wuL   = scr + 2560;     // 256
  float* vL    = wuL + 256;      // 512 = [reads(256) | h(256)] — matches Wrec k-order
  float* cL    = vL + 512;       // 256
  float* kL    = cL + 256;       // 256
  float* WoutL = kL + 256;       // 2560   -> total 27136 floats = 108544 B
  float* pL    = scr;            // epilogue logit partials alias
  __shared__ unsigned long long redU[8];
  __shared__ int luS[4];
  __shared__ float alphaS[4];
  __shared__ float kinv[4];
  __shared__ float logitS[8];
  __shared__ float boutS[8];

  const int tid = threadIdx.x;
  const int b   = blockIdx.x;
  const int col0  = (tid & 255) * 4;   // GEMV: 4 gate cols owned
  const int khalf = tid >> 8;          // K-half (0: reads, 1: h)

  // ---- init persistent per-batch state ----
#pragma unroll
  for (int it = 0; it < 32; ++it){
    int i = it*512 + tid;
    Ms[(i >> 6)*65 + (i & 63)] = 1e-6f;
  }
  wrL[tid] = 1.f/256.f; wrL[512+tid] = 1.f/256.f;
  vL[tid] = 0.f;
  if (tid < 256){ wuL[tid] = 1.f/256.f; cL[tid] = 0.f; }
  for (int i = tid; i < 2560; i += 512) WoutL[i] = Wout[i];
  if (tid < 5) boutS[tid] = bout[tid];
  __syncthreads();

  for (int t = 0; t < TT; ++t){
    // ---- phase 1: GEMV partials, bf16 weights, K split by khalf ----
    float4 xq;
    if (tid < 256) xq = *(const float4*)(Xp + ((size_t)t*256 + b)*1024 + col0);
    {
      float4 acc4 = make_float4(0.f, 0.f, 0.f, 0.f);
      const uint* Wp = Wpk + col0;
      const int kp0 = khalf*128;
      for (int kp = kp0; kp < kp0 + 128; kp += 8){
        uint4 q[2];
        float4 v01[4];
#pragma unroll
        for (int i = 0; i < 4; ++i) v01[i] = *(const float4*)&vL[2*kp + 4*i];
        const float* vv = (const float*)v01;
#pragma unroll
        for (int g = 0; g < 4; ++g){
          q[0] = *(const uint4*)(Wp + (size_t)(kp + 2*g    )*1024);
          q[1] = *(const uint4*)(Wp + (size_t)(kp + 2*g + 1)*1024);
#pragma unroll
          for (int i = 0; i < 2; ++i){
            float ve = vv[4*g + 2*i], vo = vv[4*g + 2*i + 1];
            float4 we, wo;
            we.x = blo(q[i].x); wo.x = bhi(q[i].x);
            we.y = blo(q[i].y); wo.y = bhi(q[i].y);
            we.z = blo(q[i].z); wo.z = bhi(q[i].z);
            we.w = blo(q[i].w); wo.w = bhi(q[i].w);
            FMA4(ve, we) FMA4(vo, wo)
          }
        }
      }
      *(float4*)&scr[khalf*1024 + col0] = acc4;
    }
    __syncthreads();

    // ---- phase 2: combine gate partials + Xp row ----
    if (tid < 256){
      float4 lo = *(const float4*)&scr[col0];
      float4 hi = *(const float4*)&scr[1024 + col0];
      float4 g4;
      g4.x = xq.x + lo.x + hi.x; g4.y = xq.y + lo.y + hi.y;
      g4.z = xq.z + lo.z + hi.z; g4.w = xq.w + lo.w + hi.w;
      *(float4*)&gL[col0] = g4;
    }
    __syncthreads();

    // ---- phase 3: LSTM pointwise (thread = hidden unit) ----
    if (tid < 256){
      float gi = gL[tid], gf = gL[256+tid], gg = gL[512+tid], go = gL[768+tid];
      float cn = sigf(gf)*cL[tid] + sigf(gi)*tanhf(gg);
      float hn = sigf(go)*tanhf(cn);
      cL[tid] = cn; vL[256+tid] = hn;
    }
    __syncthreads();

    // ---- phase 4: key projection partials (bf16, K-split) + alpha partials ----
    {
      const int j = tid & 255, kh2 = tid >> 8;
      float acc = 0.f;
      const uint* Wc = Wkpu + (size_t)kh2*64*256 + j;
#pragma unroll 8
      for (int ii = 0; ii < 64; ++ii){
        uint u = Wc[ii*256];
        int kk = 2*(kh2*64 + ii);
        acc = fmaf(blo(u), vL[256 + kk],     acc);
        acc = fmaf(bhi(u), vL[256 + kk + 1], acc);
      }
      scr[kh2*256 + j] = acc;
    }
    if (tid < 256){
      float hv = vL[256+tid];
      float4 wa = Wa4[tid];
      simL[tid]     = hv*wa.x;
      simL[256+tid] = hv*wa.y;
      simL[512+tid] = hv*wa.z;
      simL[768+tid] = hv*wa.w;
    }
    __syncthreads();

    // ---- phase 5: finish keys ----
    if (tid < 256) kL[tid] = tanhf(scr[tid] + scr[256+tid] + bkp[tid]);
    __syncthreads();

    // ---- phase 6: alpha + key inverse norms (waves 0..3) ----
    {
      const int w = tid >> 6, l = tid & 63;
      if (w < 4){
        float s = simL[w*256+l] + simL[w*256+64+l] + simL[w*256+128+l] + simL[w*256+192+l];
        for (int o = 32; o; o >>= 1) s += __shfl_xor(s, o, 64);
        float kv = kL[w*64 + l];
        float sq = kv*kv;
        for (int o = 32; o; o >>= 1) sq += __shfl_xor(sq, o, 64);
        if (l == 0){
          alphaS[w] = sigf(s + bkp[256 + w]);
          kinv[w]   = 1.f/(sqrtf(sq) + EPS_);
        }
      }
    }

    // ---- phase 7: top-4 argmin of w_u (ties -> lowest index) ----
    {
      unsigned long long mykey = (tid < 256)
        ? ((((unsigned long long)__float_as_uint(wuL[tid])) << 32) | (unsigned)tid)
        : ~0ull;
      for (int round = 0; round < 4; ++round){
        __syncthreads();
        unsigned long long key = mykey;
        for (int rr = 0; rr < round; ++rr) if (luS[rr] == tid) key = ~0ull;
        for (int o = 32; o; o >>= 1){
          unsigned long long other = __shfl_xor(key, o, 64);
          if (other < key) key = other;
        }
        if ((tid & 63) == 0) redU[tid >> 6] = key;
        __syncthreads();
        if (tid == 0){
          unsigned long long k0 = redU[0];
          if (redU[1] < k0) k0 = redU[1];
          if (redU[2] < k0) k0 = redU[2];
          if (redU[3] < k0) k0 = redU[3];
          luS[round] = (int)(unsigned)(k0 & 0xffffffffull);
        }
      }
    }
    __syncthreads();

    // ---- phase 8: write weights ----
    if (tid < 256){
#pragma unroll
      for (int r = 0; r < 4; ++r){
        float a = alphaS[r];
        float w = a * wrL[r*256 + tid];
        if (tid == luS[r]) w += 1.f - a;
        wwL[r*256 + tid] = w;
      }
    }
    __syncthreads();

    // ---- phase 9: erase lu[0], additive write, norm+sim partials (512 thr, d split) ----
    {
      const int n = tid & 255, d0 = (tid >> 8) * 32;
      float w0 = wwL[n], w1 = wwL[256+n], w2 = wwL[512+n], w3 = wwL[768+n];
      const bool er = (n == luS[0]);
      float* row = Ms + n*65 + d0;
      const float* kk0 = kL + d0;
      float nsq = 0.f, s0 = 0.f, s1 = 0.f, s2 = 0.f, s3 = 0.f;
#pragma unroll
      for (int d = 0; d < 32; ++d){
        float m = er ? 0.f : row[d];
        m = fmaf(w0, kk0[d],     m);
        m = fmaf(w1, kk0[64+d],  m);
        m = fmaf(w2, kk0[128+d], m);
        m = fmaf(w3, kk0[192+d], m);
        row[d] = m;
        nsq = fmaf(m, m, nsq);
        s0 = fmaf(kk0[d],     m, s0);
        s1 = fmaf(kk0[64+d],  m, s1);
        s2 = fmaf(kk0[128+d], m, s2);
        s3 = fmaf(kk0[192+d], m, s3);
      }
      scr[tid] = nsq; scr[512+tid] = s0; scr[1024+tid] = s1;
      scr[1536+tid] = s2; scr[2048+tid] = s3;
    }
    __syncthreads();

    // ---- phase 10: combine norm+sim halves ----
    if (tid < 256){
      const int n = tid;
      float nsq = scr[n] + scr[256+n];
      float minv = 1.f/(sqrtf(nsq) + EPS_);
      simL[n]     = (scr[512+n]  + scr[768+n])  * kinv[0] * minv;
      simL[256+n] = (scr[1024+n] + scr[1280+n]) * kinv[1] * minv;
      simL[512+n] = (scr[1536+n] + scr[1792+n]) * kinv[2] * minv;
      simL[768+n] = (scr[2048+n] + scr[2304+n]) * kinv[3] * minv;
    }
    __syncthreads();

    // ---- phase 11: softmax over slots (one wave per read head) ----
    if (tid < 256){
      const int r = tid >> 6, l = tid & 63;
      float v0 = simL[r*256 + l],       v1 = simL[r*256 + 64 + l],
            v2 = simL[r*256 + 128 + l], v3 = simL[r*256 + 192 + l];
      float mx = fmaxf(fmaxf(v0,v1), fmaxf(v2,v3));
      for (int o = 32; o; o >>= 1) mx = fmaxf(mx, __shfl_xor(mx, o, 64));
      float e0 = expf(v0-mx), e1 = expf(v1-mx), e2 = expf(v2-mx), e3 = expf(v3-mx);
      float s = e0+e1+e2+e3;
      for (int o = 32; o; o >>= 1) s += __shfl_xor(s, o, 64);
      float inv = 1.f/s;
      wrL[r*256 + l] = e0*inv; wrL[r*256 + 64 + l] = e1*inv;
      wrL[r*256 + 128 + l] = e2*inv; wrL[r*256 + 192 + l] = e3*inv;
    }
    __syncthreads();

    // ---- phase 12: reads partials = w_r @ M (512 thr, n split) ----
    {
      const int r = (tid >> 6) & 3, d = tid & 63, n0 = (tid >> 8) * 128;
      float acc3 = 0.f;
      for (int n = n0; n < n0 + 128; ++n)
        acc3 = fmaf(wrL[r*256+n], Ms[n*65+d], acc3);
      scr[tid] = acc3;
    }
    __syncthreads();

    // ---- phase 13: combine reads; usage update; logit partials (pL aliases scr) ----
    if (tid < 256){
      float rv = scr[tid] + scr[tid+256];
      vL[tid] = rv;
      float hv = vL[256+tid];
      float wu = GAMMA_*wuL[tid]
        + wrL[tid] + wrL[256+tid] + wrL[512+tid] + wrL[768+tid]
        + wwL[tid] + wwL[256+tid] + wwL[512+tid] + wwL[768+tid];
      wuL[tid] = wu;
      const float* W1 = WoutL + tid*5;
      const float* W2 = WoutL + (256+tid)*5;
      pL[0*256+tid] = hv*W1[0] + rv*W2[0];
      pL[1*256+tid] = hv*W1[1] + rv*W2[1];
      pL[2*256+tid] = hv*W1[2] + rv*W2[2];
      pL[3*256+tid] = hv*W1[3] + rv*W2[3];
      pL[4*256+tid] = hv*W1[4] + rv*W2[4];
    }
    __syncthreads();

    // ---- phase 14: logits (waves 0..4, one class each) + softmax + store ----
    {
      const int w = tid >> 6, l = tid & 63;
      if (w < 5){
        float s = pL[w*256+l] + pL[w*256+64+l] + pL[w*256+128+l] + pL[w*256+192+l];
        for (int o = 32; o; o >>= 1) s += __shfl_xor(s, o, 64);
        if (l == 0) logitS[w] = s + boutS[w];
      }
    }
    __syncthreads();
    if (tid == 0){
      float l0 = logitS[0], l1 = logitS[1], l2 = logitS[2], l3 = logitS[3], l4 = logitS[4];
      float mx = fmaxf(fmaxf(fmaxf(l0,l1), fmaxf(l2,l3)), l4);
      float e0 = expf(l0-mx), e1 = expf(l1-mx), e2 = expf(l2-mx), e3 = expf(l3-mx), e4 = expf(l4-mx);
      float inv = 1.f/(e0+e1+e2+e3+e4);
      float* o5 = out + ((size_t)b*TT + t)*NCL;
      o5[0] = e0*inv; o5[1] = e1*inv; o5[2] = e2*inv; o5[3] = e3*inv; o5[4] = e4*inv;
    }
    __syncthreads();
  }
}

extern "C" void kernel_launch(void* const* d_in, const int* in_sizes, int n_in,
                              void* d_out, int out_size, void* d_ws, size_t ws_size,
                              hipStream_t stream)
{
  (void)in_sizes; (void)n_in; (void)out_size; (void)ws_size;
  const float* X    = (const float*)d_in[0];
  const int*   tgt  = (const int*)d_in[1];
  const float* Wih  = (const float*)d_in[2];
  const float* Whh  = (const float*)d_in[3];
  const float* bl   = (const float*)d_in[4];
  const float* Wkp  = (const float*)d_in[5];
  const float* bkp  = (const float*)d_in[6];
  const float* Wout = (const float*)d_in[7];
  const float* bout = (const float*)d_in[8];
  float* out = (float*)d_out;

  float* Xp   = (float*)d_ws;              // 13,107,200 floats [T*B, 1024]
  uint*  Wpk  = (uint*)(Xp + 13107200);    // 262,144 uints  (512x1024 bf16 pairs)
  uint*  Wkpu = Wpk + 262144;              //  32,768 uints  (256x256 bf16 pairs)
  float4* Wa4 = (float4*)(Wkpu + 32768);   //     256 float4 (alpha cols fp32)

  hipFuncSetAttribute(reinterpret_cast<const void*>(k_batch),
                      hipFuncAttributeMaxDynamicSharedMemorySize, 108544);

  k_pack<<<1153, 256, 0, stream>>>(Wih, Whh, Wkp, Wpk, Wkpu, Wa4);
  k_xproj<<<dim3(200,16), 256, 0, stream>>>(X, tgt, Wih, bl, Xp);
  k_batch<<<256, 512, 108544, stream>>>(Xp, Wpk, Wkpu, Wa4, bkp, Wout, bout, out);
}